// Round 4
// baseline (79.301 us; speedup 1.0000x reference)
//
#include <hip/hip_runtime.h>

typedef float f2 __attribute__((ext_vector_type(2)));

namespace {
constexpr int kB = 4;
constexpr int kN = 4096;             // points per set per batch (N == M)
constexpr int kPts = kB * kN;        // per set = 16384
constexpr int kP = 2 * kPts;         // all per-point mins = 32768
constexpr int kBlk = 256;
constexpr int kOP = 2;               // own points per thread (R1 proven)
constexpr int kSplit = 16;           // blocks splitting the inner scan
constexpr int kChunk = kN / kSplit;  // 256 other-points per block
constexpr float kInf = 3.4e38f;
}

// ws layout:
//   [partials: kP * kSplit floats = 2 MB]   (no init needed — fully written)
//   [pack:     kP float4            = 512 KB]
// Pair-interleaved pack: for point pair g, float4 pack4[2g] = {x0,x1,y0,y1},
// pack4[2g+1] = {z0,z1,w0,w1}, w = ||p||^2. Pairs [0, kPts/2) = target set,
// [kPts/2, kP/2) = source set. This layout puts v_pk_fma_f32 operands in
// adjacent registers after the wave-uniform s_load_dwordx4.
//
// R3 post-mortem: device-scope atomicMin with 16-32-way same-address
// contention costs ~10 ns/op (R1->R3: +500K atomics = +5 us). This version
// has ZERO atomics in the hot kernel: each split-block stores its partial
// min (plain coalesced float2 store), reduce mins over the 16 splits.

// One thread per point PAIR: contiguous 24B read, two float4 stores.
__global__ __launch_bounds__(kBlk) void cham_prep_kernel(
    const float* __restrict__ src, const float* __restrict__ tgt,
    float4* __restrict__ pack4, float* __restrict__ out) {
  int g = blockIdx.x * kBlk + threadIdx.x;  // pair id, grid covers kP/2
  const float* p = (g < kPts / 2) ? (tgt + (size_t)g * 6)
                                  : (src + (size_t)(g - kPts / 2) * 6);
  const f2 a = *(const f2*)(p);      // {x0, y0}   (8B-aligned: 24g % 8 == 0)
  const f2 bv = *(const f2*)(p + 2); // {z0, x1}
  const f2 c = *(const f2*)(p + 4);  // {y1, z1}
  const float x0 = a.x, y0 = a.y, z0 = bv.x;
  const float x1 = bv.y, y1 = c.x, z1 = c.y;
  const float w0 = fmaf(x0, x0, fmaf(y0, y0, z0 * z0));
  const float w1 = fmaf(x1, x1, fmaf(y1, y1, z1 * z1));
  pack4[2 * g] = make_float4(x0, x1, y0, y1);
  pack4[2 * g + 1] = make_float4(z0, z1, w0, w1);
  if (g == 0) out[0] = 0.0f;
}

// R1 structure: one thread = 2 own points (read from pack4, w precomputed),
// scans a 256-point chunk of the other set via wave-uniform s_load.
// Inner 2-other group: 2 s_load_dwordx4 + 1 shared W SGPR->VGPR copy +
// per own {3 v_pk_fma (W folded into chain tail) + 1 v_min3}
//   => 2.25 VALU/eval, 4 independent min chains for ILP.
// Ends with ONE plain float2 store — no atomics, no enc/dec.
__global__ __launch_bounds__(kBlk) void cham_min_kernel(
    const float4* __restrict__ pack4, float* __restrict__ partials) {
  const int dir = blockIdx.z;  // 0: s->t (other = tgt = first half), 1: t->s
  const int b = blockIdx.y;
  const int chunk = blockIdx.x & (kSplit - 1);
  const int ntile = blockIdx.x >> 4;  // kSplit == 16
  const int tp = ntile * kBlk + threadIdx.x;  // own PAIR index within (dir,b)

  // own set: dir==0 -> src (second half of pack), dir==1 -> tgt (first half)
  const size_t ownPair =
      ((size_t)(1 - dir) * kPts + (size_t)b * kN) / 2 + (size_t)tp;
  const float4 OA = pack4[2 * ownPair];      // {x0, x1, y0, y1}
  const float4 OB = pack4[2 * ownPair + 1];  // {z0, z1, w0, w1}
  const f2 NX0 = {-2.0f * OA.x, -2.0f * OA.x};
  const f2 NY0 = {-2.0f * OA.z, -2.0f * OA.z};
  const f2 NZ0 = {-2.0f * OB.x, -2.0f * OB.x};
  const f2 NX1 = {-2.0f * OA.y, -2.0f * OA.y};
  const f2 NY1 = {-2.0f * OA.w, -2.0f * OA.w};
  const f2 NZ1 = {-2.0f * OB.y, -2.0f * OB.y};

  // other-set chunk start, in 2-point groups (2 float4s per group)
  const size_t g0 =
      ((size_t)dir * kPts + (size_t)b * kN + (size_t)chunk * kChunk) / 2;
  const float4* __restrict__ q = pack4 + 2 * g0;

  float e0a = kInf, e0b = kInf, e1a = kInf, e1b = kInf;
#pragma unroll 8
  for (int g = 0; g < kChunk / 2; ++g) {
    const float4 A = q[2 * g + 0];   // {x_a, x_b, y_a, y_b}
    const float4 Bv = q[2 * g + 1];  // {z_a, z_b, w_a, w_b}
    const f2 X = {A.x, A.y}, Y = {A.z, A.w}, Z = {Bv.x, Bv.y};
    const f2 Wv = {Bv.z, Bv.w};  // single SGPR->VGPR copy, shared
    const f2 d0 = __builtin_elementwise_fma(
        NX0, X,
        __builtin_elementwise_fma(NY0, Y,
                                  __builtin_elementwise_fma(NZ0, Z, Wv)));
    const f2 d1 = __builtin_elementwise_fma(
        NX1, X,
        __builtin_elementwise_fma(NY1, Y,
                                  __builtin_elementwise_fma(NZ1, Z, Wv)));
    if (g & 1) {  // statically resolved under unroll (8k+j -> j&1)
      e0b = fminf(fminf(d0.x, d0.y), e0b);  // v_min3
      e1b = fminf(fminf(d1.x, d1.y), e1b);
    } else {
      e0a = fminf(fminf(d0.x, d0.y), e0a);
      e1a = fminf(fminf(d1.x, d1.y), e1a);
    }
  }

  const float best0 = fminf(e0a, e0b) + OB.z;  // + ||own0||^2
  const float best1 = fminf(e1a, e1b) + OB.w;  // + ||own1||^2
  // partials[((dir*kB+b)*kSplit + chunk)][n], one float2 per thread
  float2* __restrict__ pb =
      (float2*)(partials + ((size_t)(dir * kB + b) * kSplit + chunk) * kN);
  pb[tp] = make_float2(best0, best1);
}

// For each of the kP (dir,b,n) keys: min over kSplit partials (bitwise equal
// to the old atomicMin result), then the EXACT same 16-block grid-stride +
// shared-tree summation as previous rounds (absmax stays 0).
__global__ __launch_bounds__(kBlk) void cham_reduce_kernel(
    const float* __restrict__ partials, float* __restrict__ out) {
  __shared__ float red[kBlk];
  float acc = 0.0f;
  for (int i = blockIdx.x * kBlk + threadIdx.x; i < kP; i += gridDim.x * kBlk) {
    const int db = i >> 12;        // i / kN   (kN == 4096)
    const int n = i & (kN - 1);    // i % kN
    const float* p = partials + ((size_t)db * kSplit) * kN + n;
    float m = kInf;
#pragma unroll
    for (int s = 0; s < kSplit; ++s) m = fminf(m, p[(size_t)s * kN]);
    acc += m;
  }
  red[threadIdx.x] = acc;
  __syncthreads();
  for (int s = kBlk / 2; s > 0; s >>= 1) {
    if (threadIdx.x < s) red[threadIdx.x] += red[threadIdx.x + s];
    __syncthreads();
  }
  if (threadIdx.x == 0) atomicAdd(out, red[0] * (1.0f / kPts));
}

extern "C" void kernel_launch(void* const* d_in, const int* in_sizes, int n_in,
                              void* d_out, int out_size, void* d_ws,
                              size_t ws_size, hipStream_t stream) {
  const float* src = (const float*)d_in[0];  // (B, N, 3) fp32
  const float* tgt = (const float*)d_in[1];  // (B, M, 3) fp32
  float* out = (float*)d_out;                // scalar fp32

  float* partials = (float*)d_ws;  // kP * kSplit floats = 2 MB
  float* packf =
      (float*)((char*)d_ws + (size_t)kP * kSplit * 4);  // 512 KB, 16B-align

  cham_prep_kernel<<<dim3(kP / 2 / kBlk), kBlk, 0, stream>>>(
      src, tgt, (float4*)packf, out);

  // (8 own-pair tiles * 16 splits, B, 2 dirs) = 1024 blocks, 4096 waves
  dim3 grid(kN / (kBlk * kOP) * kSplit, kB, 2);
  cham_min_kernel<<<grid, kBlk, 0, stream>>>((const float4*)packf, partials);

  cham_reduce_kernel<<<dim3(16), kBlk, 0, stream>>>(partials, out);
}

// Round 5
// 76.844 us; speedup vs baseline: 1.0320x; 1.0320x over previous
//
#include <hip/hip_runtime.h>

typedef float f2 __attribute__((ext_vector_type(2)));

namespace {
constexpr int kB = 4;
constexpr int kN = 4096;              // points per set per batch (N == M)
constexpr int kPts = kB * kN;         // per set = 16384
constexpr int kP = 2 * kPts;          // all per-point mins = 32768
constexpr int kBlkPrep = 256;
constexpr int kBlk = 512;             // 8 waves per block
constexpr int kWaves = kBlk / 64;     // 8 splits of the other set
constexpr int kChunk = kN / kWaves;   // 512 other-points per wave
constexpr int kPairsBlk = 64;         // own pairs per block (= lanes/wave)
constexpr float kInf = 3.4e38f;
}

// ws layout: [mins: kP floats = 128 KB][pack: kP float4 = 512 KB]
// Pair-interleaved pack: for point pair g, float4 pack4[2g] = {x0,x1,y0,y1},
// pack4[2g+1] = {z0,z1,w0,w1}, w = ||p||^2. Pairs [0, kPts/2) = target set,
// [kPts/2, kP/2) = source set. This layout puts v_pk_fma_f32 operands in
// adjacent registers after the wave-uniform s_load_dwordx4.
//
// R2/R3/R4 post-mortems: inverted VGPR staging spilled (-12 us), contended
// atomicMin cost ~10ns/op (+5 us), global partials + strided 16-block
// reduce cost ~8 us. R5 keeps R1's proven inner loop verbatim and moves the
// split-combine into LDS: 8 waves/block share 64 own-pairs, each wave scans
// a disjoint 512-point other-chunk, LDS tree-min, wave 0 stores final mins.
// Zero atomics, zero extra global traffic, 2 waves/SIMD for latency hiding.

// One thread per point PAIR: contiguous 24B read, two float4 stores.
__global__ __launch_bounds__(kBlkPrep) void cham_prep_kernel(
    const float* __restrict__ src, const float* __restrict__ tgt,
    float4* __restrict__ pack4, float* __restrict__ out) {
  int g = blockIdx.x * kBlkPrep + threadIdx.x;  // pair id, grid covers kP/2
  const float* p = (g < kPts / 2) ? (tgt + (size_t)g * 6)
                                  : (src + (size_t)(g - kPts / 2) * 6);
  const f2 a = *(const f2*)(p);      // {x0, y0}   (8B-aligned: 24g % 8 == 0)
  const f2 bv = *(const f2*)(p + 2); // {z0, x1}
  const f2 c = *(const f2*)(p + 4);  // {y1, z1}
  const float x0 = a.x, y0 = a.y, z0 = bv.x;
  const float x1 = bv.y, y1 = c.x, z1 = c.y;
  const float w0 = fmaf(x0, x0, fmaf(y0, y0, z0 * z0));
  const float w1 = fmaf(x1, x1, fmaf(y1, y1, z1 * z1));
  pack4[2 * g] = make_float4(x0, x1, y0, y1);
  pack4[2 * g + 1] = make_float4(z0, z1, w0, w1);
  if (g == 0) out[0] = 0.0f;
}

// Block: 8 waves x 64 lanes. lane <-> own pair (2 points, w precomputed);
// wave w scans other-chunk w (512 pts = 256 groups) with R1's loop:
// 2 wave-uniform s_load_dwordx4 + 1 shared W SGPR->VGPR copy + per own
// {3 v_pk_fma + 1 v_min3} => 2.25 VALU/eval, 4 independent min chains.
// readfirstlane forces the wave id scalar so the other-base stays SGPR
// (otherwise threadIdx-derived base demotes s_load to per-lane VMEM).
__global__ __launch_bounds__(kBlk) void cham_min_kernel(
    const float4* __restrict__ pack4, float* __restrict__ mins) {
  const int dir = blockIdx.z;  // 0: s->t (other = tgt = first half), 1: t->s
  const int b = blockIdx.y;
  const int wave = __builtin_amdgcn_readfirstlane((int)threadIdx.x >> 6);
  const int lane = threadIdx.x & 63;
  const int tp = blockIdx.x * kPairsBlk + lane;  // own PAIR within (dir,b)

  // own set: dir==0 -> src (second half of pack), dir==1 -> tgt (first half)
  const size_t ownPair =
      ((size_t)(1 - dir) * kPts + (size_t)b * kN) / 2 + (size_t)tp;
  const float4 OA = pack4[2 * ownPair];      // {x0, x1, y0, y1}
  const float4 OB = pack4[2 * ownPair + 1];  // {z0, z1, w0, w1}
  const f2 NX0 = {-2.0f * OA.x, -2.0f * OA.x};
  const f2 NY0 = {-2.0f * OA.z, -2.0f * OA.z};
  const f2 NZ0 = {-2.0f * OB.x, -2.0f * OB.x};
  const f2 NX1 = {-2.0f * OA.y, -2.0f * OA.y};
  const f2 NY1 = {-2.0f * OA.w, -2.0f * OA.w};
  const f2 NZ1 = {-2.0f * OB.y, -2.0f * OB.y};

  // this wave's other-chunk start, in 2-point groups (2 float4s per group)
  const size_t g0 =
      ((size_t)dir * kPts + (size_t)b * kN + (size_t)wave * kChunk) / 2;
  const float4* __restrict__ q = pack4 + 2 * g0;

  float e0a = kInf, e0b = kInf, e1a = kInf, e1b = kInf;
#pragma unroll 8
  for (int g = 0; g < kChunk / 2; ++g) {  // 256 groups
    const float4 A = q[2 * g + 0];   // {x_a, x_b, y_a, y_b}
    const float4 Bv = q[2 * g + 1];  // {z_a, z_b, w_a, w_b}
    const f2 X = {A.x, A.y}, Y = {A.z, A.w}, Z = {Bv.x, Bv.y};
    const f2 Wv = {Bv.z, Bv.w};  // single SGPR->VGPR copy, shared
    const f2 d0 = __builtin_elementwise_fma(
        NX0, X,
        __builtin_elementwise_fma(NY0, Y,
                                  __builtin_elementwise_fma(NZ0, Z, Wv)));
    const f2 d1 = __builtin_elementwise_fma(
        NX1, X,
        __builtin_elementwise_fma(NY1, Y,
                                  __builtin_elementwise_fma(NZ1, Z, Wv)));
    if (g & 1) {  // statically resolved under unroll (8k+j -> j&1)
      e0b = fminf(fminf(d0.x, d0.y), e0b);  // v_min3
      e1b = fminf(fminf(d1.x, d1.y), e1b);
    } else {
      e0a = fminf(fminf(d0.x, d0.y), e0a);
      e1a = fminf(fminf(d1.x, d1.y), e1a);
    }
  }

  // LDS combine across the 8 waves. [w][l] float2: lanes hit banks 2l%32 ->
  // 2-way aliasing only (free, m136). 4 KB.
  __shared__ float2 cmb[kWaves][kPairsBlk];
  cmb[wave][lane] = make_float2(fminf(e0a, e0b), fminf(e1a, e1b));
  __syncthreads();
  if (threadIdx.x < 64) {  // wave 0 holds the same pairs' OB
    float m0 = cmb[0][lane].x, m1 = cmb[0][lane].y;
#pragma unroll
    for (int w = 1; w < kWaves; ++w) {
      m0 = fminf(m0, cmb[w][lane].x);
      m1 = fminf(m1, cmb[w][lane].y);
    }
    float2* __restrict__ pb = (float2*)(mins + ((size_t)dir * kB + b) * kN);
    pb[tp] = make_float2(m0 + OB.z, m1 + OB.w);  // + ||own||^2
  }
}

// Sum all 2*B*N per-point mins, scale by 1/(B*N) (N == M). Same 16-block
// grid-stride partition + shared-tree order as R1 -> bitwise-same output.
__global__ __launch_bounds__(kBlkPrep) void cham_reduce_kernel(
    const float* __restrict__ mins, float* __restrict__ out) {
  __shared__ float red[kBlkPrep];
  float acc = 0.0f;
  for (int i = blockIdx.x * kBlkPrep + threadIdx.x; i < kP;
       i += gridDim.x * kBlkPrep)
    acc += mins[i];
  red[threadIdx.x] = acc;
  __syncthreads();
  for (int s = kBlkPrep / 2; s > 0; s >>= 1) {
    if (threadIdx.x < s) red[threadIdx.x] += red[threadIdx.x + s];
    __syncthreads();
  }
  if (threadIdx.x == 0) atomicAdd(out, red[0] * (1.0f / kPts));
}

extern "C" void kernel_launch(void* const* d_in, const int* in_sizes, int n_in,
                              void* d_out, int out_size, void* d_ws,
                              size_t ws_size, hipStream_t stream) {
  const float* src = (const float*)d_in[0];  // (B, N, 3) fp32
  const float* tgt = (const float*)d_in[1];  // (B, M, 3) fp32
  float* out = (float*)d_out;                // scalar fp32

  float* mins = (float*)d_ws;                             // 128 KB
  float* packf = (float*)((char*)d_ws + (size_t)kP * 4);  // 512 KB, 16B-align

  cham_prep_kernel<<<dim3(kP / 2 / kBlkPrep), kBlkPrep, 0, stream>>>(
      src, tgt, (float4*)packf, out);

  // (2048 pairs / 64 per block, B, 2 dirs) = 256 blocks x 512 thr
  //   = 2048 waves = 2 waves/SIMD, 1 block/CU.
  dim3 grid(kN / 2 / kPairsBlk, kB, 2);
  cham_min_kernel<<<grid, kBlk, 0, stream>>>((const float4*)packf, mins);

  cham_reduce_kernel<<<dim3(16), kBlkPrep, 0, stream>>>(mins, out);
}

// Round 6
// 71.302 us; speedup vs baseline: 1.1122x; 1.0777x over previous
//
#include <hip/hip_runtime.h>

typedef float f2 __attribute__((ext_vector_type(2)));

namespace {
constexpr int kB = 4;
constexpr int kN = 4096;              // points per set per batch (N == M)
constexpr int kPts = kB * kN;         // per set = 16384
constexpr int kP = 2 * kPts;          // all per-point mins = 32768
constexpr int kBlkPrep = 256;
constexpr int kBlk = 1024;            // 16 waves per block
constexpr int kWaves = kBlk / 64;     // 16 splits of the other set
constexpr int kChunk = kN / kWaves;   // 256 other-points per wave
constexpr int kPairsBlk = 64;         // own pairs per block (= lanes/wave)
constexpr float kInf = 3.4e38f;
}

// ws layout: [pack: kP float4 = 512 KB]
// Pair-interleaved pack: for point pair g, float4 pack4[2g] = {x0,x1,y0,y1},
// pack4[2g+1] = {z0,z1,w0,w1}, w = ||p||^2. Pairs [0, kPts/2) = target set,
// [kPts/2, kP/2) = source set. This layout puts v_pk_fma_f32 operands in
// adjacent registers after the wave-uniform s_load_dwordx4.
//
// Cross-round ledger: instr/eval is 2nd-order; 1st-order costs are
//   (a) contended atomicMin (R3: +5 us), (b) extra global round-trips
//   (R4: +8 us), (c) resident occupancy 2 vs 4 waves/SIMD (R5: +5 us).
// R6 = R5's LDS-combine with ALL THREE absent: 16-wave blocks restore
// 4 waves/SIMD (1 block/CU x 16 waves), block holds the FINAL mins for its
// 64 pairs -> fuse the whole reduce into one uncontended atomicAdd per
// block. 2 dispatches total, no mins buffer, no reduce kernel.

// One thread per point PAIR: contiguous 24B read, two float4 stores.
__global__ __launch_bounds__(kBlkPrep) void cham_prep_kernel(
    const float* __restrict__ src, const float* __restrict__ tgt,
    float4* __restrict__ pack4, float* __restrict__ out) {
  int g = blockIdx.x * kBlkPrep + threadIdx.x;  // pair id, grid covers kP/2
  const float* p = (g < kPts / 2) ? (tgt + (size_t)g * 6)
                                  : (src + (size_t)(g - kPts / 2) * 6);
  const f2 a = *(const f2*)(p);      // {x0, y0}   (8B-aligned: 24g % 8 == 0)
  const f2 bv = *(const f2*)(p + 2); // {z0, x1}
  const f2 c = *(const f2*)(p + 4);  // {y1, z1}
  const float x0 = a.x, y0 = a.y, z0 = bv.x;
  const float x1 = bv.y, y1 = c.x, z1 = c.y;
  const float w0 = fmaf(x0, x0, fmaf(y0, y0, z0 * z0));
  const float w1 = fmaf(x1, x1, fmaf(y1, y1, z1 * z1));
  pack4[2 * g] = make_float4(x0, x1, y0, y1);
  pack4[2 * g + 1] = make_float4(z0, z1, w0, w1);
  if (g == 0) out[0] = 0.0f;
}

// Block: 16 waves x 64 lanes, one block per CU. lane <-> own pair (2 points,
// w precomputed); wave w scans other-chunk w (256 pts = 128 groups) with
// R1's proven loop: 2 wave-uniform s_load_dwordx4 + 1 shared W SGPR->VGPR
// copy + per own {3 v_pk_fma + 1 v_min3} => 2.25 VALU/eval, 4 min chains.
// readfirstlane keeps the wave id in an SGPR so the other-base stays
// provably wave-uniform (preserves s_load; else demotes to per-lane VMEM).
// Tail: LDS min-combine across 16 waves, then wave 0 butterfly-sums its
// 128 final mins and lane 0 atomicAdds the scaled block partial.
__global__ __launch_bounds__(kBlk) void cham_min_kernel(
    const float4* __restrict__ pack4, float* __restrict__ out) {
  const int dir = blockIdx.z;  // 0: s->t (other = tgt = first half), 1: t->s
  const int b = blockIdx.y;
  const int wave = __builtin_amdgcn_readfirstlane((int)threadIdx.x >> 6);
  const int lane = threadIdx.x & 63;
  const int tp = blockIdx.x * kPairsBlk + lane;  // own PAIR within (dir,b)

  // own set: dir==0 -> src (second half of pack), dir==1 -> tgt (first half)
  const size_t ownPair =
      ((size_t)(1 - dir) * kPts + (size_t)b * kN) / 2 + (size_t)tp;
  const float4 OA = pack4[2 * ownPair];      // {x0, x1, y0, y1}
  const float4 OB = pack4[2 * ownPair + 1];  // {z0, z1, w0, w1}
  const f2 NX0 = {-2.0f * OA.x, -2.0f * OA.x};
  const f2 NY0 = {-2.0f * OA.z, -2.0f * OA.z};
  const f2 NZ0 = {-2.0f * OB.x, -2.0f * OB.x};
  const f2 NX1 = {-2.0f * OA.y, -2.0f * OA.y};
  const f2 NY1 = {-2.0f * OA.w, -2.0f * OA.w};
  const f2 NZ1 = {-2.0f * OB.y, -2.0f * OB.y};

  // this wave's other-chunk start, in 2-point groups (2 float4s per group)
  const size_t g0 =
      ((size_t)dir * kPts + (size_t)b * kN + (size_t)wave * kChunk) / 2;
  const float4* __restrict__ q = pack4 + 2 * g0;

  float e0a = kInf, e0b = kInf, e1a = kInf, e1b = kInf;
#pragma unroll 8
  for (int g = 0; g < kChunk / 2; ++g) {  // 128 groups
    const float4 A = q[2 * g + 0];   // {x_a, x_b, y_a, y_b}
    const float4 Bv = q[2 * g + 1];  // {z_a, z_b, w_a, w_b}
    const f2 X = {A.x, A.y}, Y = {A.z, A.w}, Z = {Bv.x, Bv.y};
    const f2 Wv = {Bv.z, Bv.w};  // single SGPR->VGPR copy, shared
    const f2 d0 = __builtin_elementwise_fma(
        NX0, X,
        __builtin_elementwise_fma(NY0, Y,
                                  __builtin_elementwise_fma(NZ0, Z, Wv)));
    const f2 d1 = __builtin_elementwise_fma(
        NX1, X,
        __builtin_elementwise_fma(NY1, Y,
                                  __builtin_elementwise_fma(NZ1, Z, Wv)));
    if (g & 1) {  // statically resolved under unroll (8k+j -> j&1)
      e0b = fminf(fminf(d0.x, d0.y), e0b);  // v_min3
      e1b = fminf(fminf(d1.x, d1.y), e1b);
    } else {
      e0a = fminf(fminf(d0.x, d0.y), e0a);
      e1a = fminf(fminf(d1.x, d1.y), e1a);
    }
  }

  // LDS min-combine across the 16 waves (8 KB; tiny access count).
  __shared__ float2 cmb[kWaves][kPairsBlk];
  cmb[wave][lane] = make_float2(fminf(e0a, e0b), fminf(e1a, e1b));
  __syncthreads();
  if (threadIdx.x < 64) {  // wave 0 holds the same pairs' OB
    float m0 = cmb[0][lane].x, m1 = cmb[0][lane].y;
#pragma unroll
    for (int w = 1; w < kWaves; ++w) {
      m0 = fminf(m0, cmb[w][lane].x);
      m1 = fminf(m1, cmb[w][lane].y);
    }
    // final per-point mins for this block's 128 points; sum and emit once
    float s = (m0 + OB.z) + (m1 + OB.w);  // + ||own||^2
#pragma unroll
    for (int m = 1; m < 64; m <<= 1) s += __shfl_xor(s, m, 64);
    if (lane == 0) atomicAdd(out, s * (1.0f / kPts));
  }
}

extern "C" void kernel_launch(void* const* d_in, const int* in_sizes, int n_in,
                              void* d_out, int out_size, void* d_ws,
                              size_t ws_size, hipStream_t stream) {
  const float* src = (const float*)d_in[0];  // (B, N, 3) fp32
  const float* tgt = (const float*)d_in[1];  // (B, M, 3) fp32
  float* out = (float*)d_out;                // scalar fp32

  float* packf = (float*)d_ws;  // kP float4 = 512 KB, 16B-aligned

  cham_prep_kernel<<<dim3(kP / 2 / kBlkPrep), kBlkPrep, 0, stream>>>(
      src, tgt, (float4*)packf, out);

  // (2048 pairs / 64 per block, B, 2 dirs) = 256 blocks x 1024 thr
  //   = 1 block/CU, 16 waves/CU = 4 waves/SIMD resident (R1 occupancy).
  dim3 grid(kN / 2 / kPairsBlk, kB, 2);
  cham_min_kernel<<<grid, kBlk, 0, stream>>>((const float4*)packf, out);
}